// Round 17
// baseline (306.075 us; speedup 1.0000x reference)
//
#include <hip/hip_runtime.h>
#include <stdint.h>
#include <stddef.h>

#define B_SZ 32
#define NQ 577
#define CDIM 768
#define NH 12
#define HDIM 64
#define MROWS (B_SZ * NQ)     // 18464
#define KDIM CDIM             // 768
#define NKT (KDIM / 64)       // 12 K-tiles of 64 (proj 8-phase)
#define VT_STRIDE 640
#define MK_STRIDE 640
#define SCALE_F 0.125f

typedef __bf16 bf16x8 __attribute__((ext_vector_type(8)));
typedef float f32x4 __attribute__((ext_vector_type(4)));
typedef unsigned short u16x8 __attribute__((ext_vector_type(8)));
typedef unsigned short u16x4 __attribute__((ext_vector_type(4)));

__device__ __forceinline__ unsigned short f2bf(float f) {
    unsigned int u = __builtin_bit_cast(unsigned int, f);
    return (unsigned short)((u + 0x7fffu + ((u >> 16) & 1u)) >> 16);  // RNE
}
__device__ __forceinline__ float bf2f(unsigned short u) {
    unsigned int v = ((unsigned int)u) << 16;
    return __builtin_bit_cast(float, v);
}

__device__ __forceinline__ f32x4 mfma16(bf16x8 a, bf16x8 b, f32x4 c) {
    return __builtin_amdgcn_mfma_f32_16x16x32_bf16(a, b, c, 0, 0, 0);
}

__device__ __forceinline__ void gll16(const void* g, void* l) {
    __builtin_amdgcn_global_load_lds(
        (const __attribute__((address_space(1))) void*)g,
        (__attribute__((address_space(3))) void*)l, 16, 0, 0);
}

// ---------------- fp32 -> bf16 bulk convert
__global__ __launch_bounds__(256) void cvt_bf16(
    const float* __restrict__ src, unsigned short* __restrict__ dst, int n8)
{
    int i = blockIdx.x * blockDim.x + threadIdx.x;
    int stride = gridDim.x * blockDim.x;
    for (; i < n8; i += stride) {
        const float* p = src + (size_t)i * 8;
        f32x4 v0 = *(const f32x4*)p;
        f32x4 v1 = *(const f32x4*)(p + 4);
        u16x8 u;
        u[0] = f2bf(v0[0]); u[1] = f2bf(v0[1]); u[2] = f2bf(v0[2]); u[3] = f2bf(v0[3]);
        u[4] = f2bf(v1[0]); u[5] = f2bf(v1[1]); u[6] = f2bf(v1[2]); u[7] = f2bf(v1[3]);
        *(u16x8*)(dst + (size_t)i * 8) = u;
    }
}

// ---------------- mask fp32 [6924][577] -> bf16 [6924][640] (zero-padded)
__global__ __launch_bounds__(256) void cvt_mask(
    const float* __restrict__ src, unsigned short* __restrict__ dst)
{
    const int CH = MK_STRIDE / 8;  // 80
    int i = blockIdx.x * blockDim.x + threadIdx.x;
    int total = NH * NQ * CH;
    if (i >= total) return;
    int row = i / CH, c8 = (i % CH) * 8;
    const float* s = src + (size_t)row * NQ;
    u16x8 u;
#pragma unroll
    for (int j = 0; j < 8; ++j) {
        int c = c8 + j;
        u[j] = (c < NQ) ? f2bf(s[c]) : (unsigned short)0;
    }
    *(u16x8*)(dst + (size_t)row * MK_STRIDE + c8) = u;
}

// ---------------- Stage 1: QKV GEMM (128^2, TRIPLE-buffered, prefetch depth 2)
// Round-15 exact (best measured passing config). Trailing barrier REQUIRED:
// stage of buf[(ks+2)%3] is issued before the leading barrier, so the trailing
// barrier of the prior step is what orders slow waves' reads before overwrite
// (r16 removal -> absmax 0.064 race, reverted).
__global__ __launch_bounds__(256) void qkv_gemm(
    const unsigned short* __restrict__ A,
    const unsigned short* __restrict__ Bm,
    unsigned short* __restrict__ qb,
    unsigned short* __restrict__ kb,
    unsigned short* __restrict__ vtb)
{
    __shared__ unsigned short As[3][128 * 32];   // 24 KB
    __shared__ unsigned short Bs[3][128 * 32];   // 24 KB
    const int tid = threadIdx.x;
    const int wv = tid >> 6, lane = tid & 63;
    const int lo = lane & 15, hi = lane >> 4;
    const int wr = wv >> 1, wc = wv & 1;

    const int NT = 18;
    // bijective XCD swizzle: nwg=2610, q=326, r=2
    const int q8 = 326, r8 = 2;
    const int xcd = blockIdx.x & 7, off = blockIdx.x >> 3;
    const int wgid = (xcd < r8 ? xcd * (q8 + 1) : r8 * (q8 + 1) + (xcd - r8) * q8) + off;
    const int nt = wgid % NT, mt = wgid / NT;

    f32x4 acc[4][4];
#pragma unroll
    for (int i = 0; i < 4; ++i)
#pragma unroll
        for (int j = 0; j < 4; ++j) acc[i][j] = (f32x4){0.f, 0.f, 0.f, 0.f};

    const int c0 = wv * 128 + lane;
    const int c1 = c0 + 64;
    const int rA0 = c0 >> 2, kA0 = (c0 & 3) * 8;
    const int rA1 = c1 >> 2, kA1 = (c1 & 3) * 8;
    int gra0 = mt * 128 + rA0; if (gra0 >= MROWS) gra0 = MROWS - 1;
    int gra1 = mt * 128 + rA1; if (gra1 >= MROWS) gra1 = MROWS - 1;
    const int grb0 = nt * 128 + rA0, grb1 = nt * 128 + rA1;

#define QKV_STG(BUF, KS)                                                      \
    {                                                                         \
        const int _k = (KS) * 32;                                             \
        gll16(A  + (size_t)gra0 * KDIM + _k + kA0, &As[BUF][c0 * 8]);         \
        gll16(A  + (size_t)gra1 * KDIM + _k + kA1, &As[BUF][c1 * 8]);         \
        gll16(Bm + (size_t)grb0 * KDIM + _k + kA0, &Bs[BUF][c0 * 8]);         \
        gll16(Bm + (size_t)grb1 * KDIM + _k + kA1, &Bs[BUF][c1 * 8]);         \
    }

    QKV_STG(0, 0)
    QKV_STG(1, 1)

    for (int ks = 0; ks < 24; ++ks) {
        const int cur = ks % 3;
        if (ks + 2 < 24) {
            QKV_STG((ks + 2) % 3, ks + 2)
            asm volatile("s_waitcnt vmcnt(8)" ::: "memory");
        } else if (ks + 1 < 24) {
            asm volatile("s_waitcnt vmcnt(4)" ::: "memory");
        } else {
            asm volatile("s_waitcnt vmcnt(0)" ::: "memory");
        }
        __builtin_amdgcn_s_barrier();
        bf16x8 af[4], bfr[4];
#pragma unroll
        for (int mi = 0; mi < 4; ++mi)
            af[mi] = *(const bf16x8*)(&As[cur][(wr * 64 + mi * 16 + lo) * 32 + hi * 8]);
#pragma unroll
        for (int nj = 0; nj < 4; ++nj)
            bfr[nj] = *(const bf16x8*)(&Bs[cur][(wc * 64 + nj * 16 + lo) * 32 + hi * 8]);
        __builtin_amdgcn_s_setprio(1);
#pragma unroll
        for (int mi = 0; mi < 4; ++mi)
#pragma unroll
            for (int nj = 0; nj < 4; ++nj)
                acc[mi][nj] = mfma16(af[mi], bfr[nj], acc[mi][nj]);
        __builtin_amdgcn_s_setprio(0);
        __builtin_amdgcn_s_barrier();
    }
#undef QKV_STG

    const int s = nt / 6;
    const int h = (nt % 6) * 2 + wc;
#pragma unroll
    for (int mi = 0; mi < 4; ++mi) {
#pragma unroll
        for (int r = 0; r < 4; ++r) {
            int m = mt * 128 + wr * 64 + mi * 16 + hi * 4 + r;
            if (m >= MROWS) continue;
            int b = m / NQ, n = m % NQ;
            size_t bh = (size_t)(b * NH + h);
#pragma unroll
            for (int nj = 0; nj < 4; ++nj) {
                int d = nj * 16 + lo;
                unsigned short bv = f2bf(acc[mi][nj][r]);
                if (s == 0)      qb[(bh * NQ + n) * HDIM + d] = bv;
                else if (s == 1) kb[(bh * NQ + n) * HDIM + d] = bv;
                else             vtb[(bh * HDIM + d) * VT_STRIDE + n] = bv;
            }
        }
    }
}

// ================= 256x256x(BK=64) 8-phase template (proj only; round-11 exact) ==
#define STAGE_HT8(SC, A_PTR, B_PTR)                                                \
    { const int _t = (SC) >> 2, _p = (SC) & 3;                                     \
      if (_t < NKT) {                                                              \
        const int _kh = _p >> 1;                                                   \
        unsigned short* _dst = (_p & 1) ? &Bl[_t & 1][_kh][0] : &Al[_t & 1][_kh][0];\
        const unsigned short* _sb = (_p & 1) ? (B_PTR) : (A_PTR);                  \
        const int _rb = ((_p & 1) ? nt : mt) * 256;                                \
        const int _k = _t * 64 + _kh * 32;                                         \
        const int _c0 = tid, _c1 = tid + 512;                                      \
        const int _g0 = _c0 ^ ((_c0 >> 3) & 7), _g1 = _c1 ^ ((_c1 >> 3) & 7);      \
        int _r0 = _rb + (_g0 >> 2), _r1 = _rb + (_g1 >> 2);                        \
        if (!(_p & 1)) {                                                           \
            if (_r0 >= MROWS) _r0 = MROWS - 1;                                     \
            if (_r1 >= MROWS) _r1 = MROWS - 1;                                     \
        }                                                                          \
        gll16(_sb + (size_t)_r0 * KDIM + _k + (_g0 & 3) * 8, _dst + _c0 * 8);      \
        gll16(_sb + (size_t)_r1 * KDIM + _k + (_g1 & 3) * 8, _dst + _c1 * 8);      \
      } else {                                                                     \
        gll16(A_PTR, &Scr[tid * 8]);                                               \
        gll16(A_PTR, &Scr[(tid + 512) * 8]);                                       \
      } }

#define GEMM8_MAINLOOP(A_PTR, B_PTR)                                               \
    const int tid = threadIdx.x;                                                   \
    const int wid = tid >> 6, lane = tid & 63;                                     \
    const int lo = lane & 15, hi = lane >> 4;                                      \
    const int wr = wid >> 2, wcN = wid & 3;                                        \
    f32x4 acc[8][4];                                                               \
    _Pragma("unroll") for (int i = 0; i < 8; ++i)                                  \
        _Pragma("unroll") for (int j = 0; j < 4; ++j)                              \
            acc[i][j] = (f32x4){0.f, 0.f, 0.f, 0.f};                               \
    const int xsw = ((4 * lo + hi) ^ ((lo >> 1) & 7)) * 16;                        \
    _Pragma("unroll") for (int ps = 0; ps < 7; ++ps) { STAGE_HT8(ps, A_PTR, B_PTR) } \
    int sc = 7;                                                                    \
    asm volatile("s_waitcnt vmcnt(6)" ::: "memory");                               \
    __builtin_amdgcn_s_barrier();                                                  \
    for (int t = 0; t < NKT; ++t) {                                                \
        const int db = t & 1;                                                      \
        const char* a0p = (const char*)&Al[db][0][0] + xsw;                        \
        const char* a1p = (const char*)&Al[db][1][0] + xsw;                        \
        const char* b0p = (const char*)&Bl[db][0][0] + xsw;                        \
        const char* b1p = (const char*)&Bl[db][1][0] + xsw;                        \
        bf16x8 a[8], bx[2], by[2];                                                 \
        _Pragma("unroll") for (int mi = 0; mi < 8; ++mi)                           \
            a[mi] = *(const bf16x8*)(a0p + (wr * 8 + mi) * 1024);                  \
        bx[0] = *(const bf16x8*)(b0p + (wcN * 4 + 0) * 1024);                      \
        bx[1] = *(const bf16x8*)(b0p + (wcN * 4 + 1) * 1024);                      \
        asm volatile("" ::: "memory");                                             \
        STAGE_HT8(sc, A_PTR, B_PTR) ++sc;                                          \
        __builtin_amdgcn_s_barrier();                                              \
        __builtin_amdgcn_s_setprio(1);                                             \
        _Pragma("unroll") for (int mi = 0; mi < 8; ++mi) {                         \
            acc[mi][0] = mfma16(a[mi], bx[0], acc[mi][0]);                         \
            acc[mi][1] = mfma16(a[mi], bx[1], acc[mi][1]);                         \
        }                                                                          \
        __builtin_amdgcn_s_setprio(0);                                             \
        __builtin_amdgcn_s_barrier();                                              \
        by[0] = *(const bf16x8*)(b0p + (wcN * 4 + 2) * 1024);                      \
        by[1] = *(const bf16x8*)(b0p + (wcN * 4 + 3) * 1024);                      \
        asm volatile("" ::: "memory");                                             \
        STAGE_HT8(sc, A_PTR, B_PTR) ++sc;                                          \
        __builtin_amdgcn_s_barrier();                                              \
        __builtin_amdgcn_s_setprio(1);                                             \
        _Pragma("unroll") for (int mi = 0; mi < 8; ++mi) {                         \
            acc[mi][2] = mfma16(a[mi], by[0], acc[mi][2]);                         \
            acc[mi][3] = mfma16(a[mi], by[1], acc[mi][3]);                         \
        }                                                                          \
        __builtin_amdgcn_s_setprio(0);                                             \
        __builtin_amdgcn_s_barrier();                                              \
        _Pragma("unroll") for (int mi = 0; mi < 8; ++mi)                           \
            a[mi] = *(const bf16x8*)(a1p + (wr * 8 + mi) * 1024);                  \
        bx[0] = *(const bf16x8*)(b1p + (wcN * 4 + 0) * 1024);                      \
        bx[1] = *(const bf16x8*)(b1p + (wcN * 4 + 1) * 1024);                      \
        asm volatile("" ::: "memory");                                             \
        STAGE_HT8(sc, A_PTR, B_PTR) ++sc;                                          \
        __builtin_amdgcn_s_barrier();                                              \
        __builtin_amdgcn_s_setprio(1);                                             \
        _Pragma("unroll") for (int mi = 0; mi < 8; ++mi) {                         \
            acc[mi][0] = mfma16(a[mi], bx[0], acc[mi][0]);                         \
            acc[mi][1] = mfma16(a[mi], bx[1], acc[mi][1]);                         \
        }                                                                          \
        __builtin_amdgcn_s_setprio(0);                                             \
        __builtin_amdgcn_s_barrier();                                              \
        by[0] = *(const bf16x8*)(b1p + (wcN * 4 + 2) * 1024);                      \
        by[1] = *(const bf16x8*)(b1p + (wcN * 4 + 3) * 1024);                      \
        asm volatile("" ::: "memory");                                             \
        STAGE_HT8(sc, A_PTR, B_PTR) ++sc;                                          \
        asm volatile("s_waitcnt vmcnt(6)" ::: "memory");                           \
        __builtin_amdgcn_s_barrier();                                              \
        __builtin_amdgcn_s_setprio(1);                                             \
        _Pragma("unroll") for (int mi = 0; mi < 8; ++mi) {                         \
            acc[mi][2] = mfma16(a[mi], by[0], acc[mi][2]);                         \
            acc[mi][3] = mfma16(a[mi], by[1], acc[mi][3]);                         \
        }                                                                          \
        __builtin_amdgcn_s_setprio(0);                                             \
        __builtin_amdgcn_s_barrier();                                              \
    }                                                                              \
    asm volatile("s_waitcnt vmcnt(0)" ::: "memory");

// ---------------- Stage 3: proj GEMM (256^2 8-phase; fp32 out + bias)
__global__ __launch_bounds__(512, 2) void proj_gemm(
    const unsigned short* __restrict__ A,
    const unsigned short* __restrict__ Bm,
    const float* __restrict__ bias,
    float* __restrict__ out)
{
    __shared__ __align__(16) unsigned short Al[2][2][256 * 32];
    __shared__ __align__(16) unsigned short Bl[2][2][256 * 32];
    __shared__ __align__(16) unsigned short Scr[512 * 16];
    const int NTL = 3;   // 768/256
    // nwg = 219 = 8*27+3 -> q=27, r=3
    const int xcd = blockIdx.x & 7, off = blockIdx.x >> 3;
    const int wgid = (xcd < 3 ? xcd * 28 : 84 + (xcd - 3) * 27) + off;
    const int nt = wgid % NTL, mt = wgid / NTL;

    GEMM8_MAINLOOP(A, Bm)

    const int cb = nt * 256 + wcN * 64;
    float bv[4];
#pragma unroll
    for (int nj = 0; nj < 4; ++nj) bv[nj] = bias[cb + nj * 16 + lo];
#pragma unroll
    for (int mi = 0; mi < 8; ++mi) {
#pragma unroll
        for (int r = 0; r < 4; ++r) {
            int m = mt * 256 + wr * 128 + mi * 16 + 4 * hi + r;
            if (m >= MROWS) continue;
#pragma unroll
            for (int nj = 0; nj < 4; ++nj)
                out[(size_t)m * CDIM + cb + nj * 16 + lo] = acc[mi][nj][r] + bv[nj];
        }
    }
}

// ---------------- Stage 2: flash attention (round-11 exact: K+V LDS-staged,
// counted vmcnt(8), XOR-swizzled tiles — proven rounds 7-15)
#define STAGE(SEL, KV)                                                        \
    {                                                                         \
        int kr0 = (KV) + srow;      if (kr0 > NQ - 1) kr0 = NQ - 1;           \
        int kr1 = (KV) + srow + 32; if (kr1 > NQ - 1) kr1 = NQ - 1;           \
        gll16(kp + (size_t)kr0 * HDIM + scol, &Ks[SEL][0] + tid * 8);         \
        gll16(kp + (size_t)kr1 * HDIM + scol, &Ks[SEL][2048] + tid * 8);      \
        gll16(vp + (size_t)srow * VT_STRIDE + (KV) + scol, &Vs[SEL][0] + tid * 8); \
        gll16(vp + (size_t)(srow + 32) * VT_STRIDE + (KV) + scol, &Vs[SEL][2048] + tid * 8); \
    }

#define LOADM(MW, KV)                                                         \
    _Pragma("unroll") for (int nj = 0; nj < 4; ++nj)                          \
        MW[nj] = *(const u16x4*)(mrow + (KV) + 16 * nj + 4 * hi);

#define ATTN_COMPUTE(CB, KV)                                                  \
    {                                                                         \
        const int kv0 = (KV);                                                 \
        bf16x8 af0[4], af1[4], bv0[4], bv1[4];                                \
        _Pragma("unroll") for (int nj = 0; nj < 4; ++nj) {                    \
            int kr = 16 * nj + lo;                                            \
            int sw = (kr & 7) << 4;                                           \
            const unsigned short* rowp = &Ks[CB][kr * 64];                    \
            af0[nj] = *(const bf16x8*)(rowp + ((( 0 + 16 * hi) ^ sw) >> 1));  \
            af1[nj] = *(const bf16x8*)(rowp + (((64 + 16 * hi) ^ sw) >> 1));  \
        }                                                                     \
        _Pragma("unroll") for (int dj = 0; dj < 4; ++dj) {                    \
            int dr = 16 * dj + lo;                                            \
            int sw = (dr & 7) << 4;                                           \
            const unsigned short* rowp = &Vs[CB][dr * 64];                    \
            bv0[dj] = *(const bf16x8*)(rowp + ((( 0 + 16 * hi) ^ sw) >> 1));  \
            bv1[dj] = *(const bf16x8*)(rowp + (((64 + 16 * hi) ^ sw) >> 1));  \
        }                                                                     \
        __builtin_amdgcn_s_setprio(1);                                        \
        f32x4 S[4];                                                           \
        _Pragma("unroll") for (int nj = 0; nj < 4; ++nj) {                    \
            f32x4 sv = (f32x4){0.f, 0.f, 0.f, 0.f};                           \
            sv = mfma16(af0[nj], bq0, sv);                                    \
            sv = mfma16(af1[nj], bq1, sv);                                    \
            S[nj] = sv;                                                       \
        }                                                                     \
        __builtin_amdgcn_s_setprio(0);                                        \
        float p[16];                                                          \
        _Pragma("unroll") for (int nj = 0; nj < 4; ++nj)                      \
            _Pragma("unroll") for (int r = 0; r < 4; ++r)                     \
                p[nj * 4 + r] = S[nj][r] * SCALE_F + bf2f(mw[nj][r]);         \
        if (kv0 + 64 > NQ) {                                                  \
            const int rem = NQ - kv0;                                         \
            _Pragma("unroll") for (int nj = 0; nj < 4; ++nj)                  \
                _Pragma("unroll") for (int r = 0; r < 4; ++r)                 \
                    if (16 * nj + 4 * hi + r >= rem) p[nj * 4 + r] = -1e30f;  \
        }                                                                     \
        float m01 = fmaxf(p[0], p[1]),  m23 = fmaxf(p[2], p[3]);              \
        float m45 = fmaxf(p[4], p[5]),  m67 = fmaxf(p[6], p[7]);              \
        float m89 = fmaxf(p[8], p[9]),  mab = fmaxf(p[10], p[11]);            \
        float mcd = fmaxf(p[12], p[13]), mef = fmaxf(p[14], p[15]);           \
        float pmax = fmaxf(fmaxf(fmaxf(m01, m23), fmaxf(m45, m67)),           \
                           fmaxf(fmaxf(m89, mab), fmaxf(mcd, mef)));          \
        pmax = fmaxf(pmax, __shfl_xor(pmax, 16));                             \
        pmax = fmaxf(pmax, __shfl_xor(pmax, 32));                             \
        bool grow = pmax > m_run + 8.f;                                       \
        float mnew = grow ? pmax : m_run;                                     \
        float corr = __expf(m_run - mnew);                                    \
        m_run = mnew;                                                         \
        if (__any((int)grow)) {                                               \
            float c0 = __shfl(corr, 4 * hi + 0);                              \
            float c1 = __shfl(corr, 4 * hi + 1);                              \
            float c2 = __shfl(corr, 4 * hi + 2);                              \
            float c3 = __shfl(corr, 4 * hi + 3);                              \
            _Pragma("unroll") for (int dj = 0; dj < 4; ++dj) {                \
                accO[dj][0] *= c0; accO[dj][1] *= c1;                         \
                accO[dj][2] *= c2; accO[dj][3] *= c3;                         \
            }                                                                 \
        }                                                                     \
        _Pragma("unroll") for (int i = 0; i < 16; ++i)                        \
            p[i] = __expf(p[i] - mnew);                                       \
        float ps = (((p[0]+p[1])+(p[2]+p[3])) + ((p[4]+p[5])+(p[6]+p[7])))    \
                 + (((p[8]+p[9])+(p[10]+p[11])) + ((p[12]+p[13])+(p[14]+p[15])));\
        _Pragma("unroll") for (int nj = 0; nj < 4; ++nj) {                    \
            u16x4 w;                                                          \
            w[0] = f2bf(p[nj*4+0]); w[1] = f2bf(p[nj*4+1]);                   \
            w[2] = f2bf(p[nj*4+2]); w[3] = f2bf(p[nj*4+3]);                   \
            *(u16x4*)&P_lds[wv][lo][16 * nj + 4 * hi] = w;                    \
        }                                                                     \
        ps += __shfl_xor(ps, 16);                                             \
        ps += __shfl_xor(ps, 32);                                             \
        l_run = l_run * corr + ps;                                            \
        const bf16x8 pa0 = *(const bf16x8*)&P_lds[wv][lo][8 * hi];            \
        const bf16x8 pa1 = *(const bf16x8*)&P_lds[wv][lo][32 + 8 * hi];       \
        __builtin_amdgcn_s_setprio(1);                                        \
        _Pragma("unroll") for (int dj = 0; dj < 4; ++dj) {                    \
            accO[dj] = mfma16(pa0, bv0[dj], accO[dj]);                        \
            accO[dj] = mfma16(pa1, bv1[dj], accO[dj]);                        \
        }                                                                     \
        __builtin_amdgcn_s_setprio(0);                                        \
    }

__global__ __launch_bounds__(256) void attn_fused(
    const unsigned short* __restrict__ qb,
    const unsigned short* __restrict__ kb,
    const unsigned short* __restrict__ vtb,
    const unsigned short* __restrict__ maskb,  // [12][577][640] bf16
    unsigned short* __restrict__ ob)           // [B][577][768] bf16
{
    __shared__ unsigned short Ks[2][64 * 64];   // 16 KB
    __shared__ unsigned short Vs[2][64 * 64];   // 16 KB
    __shared__ unsigned short P_lds[4][16][68]; // 8.7 KB
    const int tid = threadIdx.x;
    const int wv = tid >> 6;
    const int lane = tid & 63;
    const int lo = lane & 15, hi = lane >> 4;

    const int xcd = blockIdx.x & 7;
    const int idx = blockIdx.x >> 3;
    const int bh = xcd + 8 * (idx / 10);
    const int qblk = idx % 10;
    const int b = bh / NH, h = bh % NH;
    const int qt0 = qblk * 64;

    const unsigned short* qp = qb + (size_t)bh * NQ * HDIM;
    const unsigned short* kp = kb + (size_t)bh * NQ * HDIM;
    const unsigned short* vp = vtb + (size_t)bh * HDIM * VT_STRIDE;

    const int srow = tid >> 3;                                  // 0..31
    const int scol = ((((tid & 7) << 4) ^ ((srow & 7) << 4)) >> 1); // swizzled src elem

    int qr = qt0 + 16 * wv + lo; if (qr > NQ - 1) qr = NQ - 1;
    const unsigned short* mrow = maskb + ((size_t)h * NQ + qr) * MK_STRIDE;
    const bf16x8 bq0 = *(const bf16x8*)(qp + (size_t)qr * HDIM + 8 * hi);
    const bf16x8 bq1 = *(const bf16x8*)(qp + (size_t)qr * HDIM + 32 + 8 * hi);

    float m_run = -1e30f, l_run = 0.f;
    f32x4 accO[4];
#pragma unroll
    for (int dj = 0; dj < 4; ++dj) accO[dj] = (f32x4){0.f, 0.f, 0.f, 0.f};

    u16x4 mw[4];
    STAGE(0, 0)
    for (int t = 0; t < 9; ++t) {
        const int kv0 = t * 64;
        LOADM(mw, kv0)
        asm volatile("" ::: "memory");
        STAGE((t + 1) & 1, kv0 + 64)
        asm volatile("s_waitcnt vmcnt(8)" ::: "memory");
        __builtin_amdgcn_s_barrier();
        asm volatile("" ::: "memory");
        ATTN_COMPUTE(t & 1, kv0)
        asm volatile("" ::: "memory");
        __builtin_amdgcn_s_barrier();
    }
    LOADM(mw, 576)
    asm volatile("s_waitcnt vmcnt(4)" ::: "memory");
    __builtin_amdgcn_s_barrier();
    asm volatile("" ::: "memory");
    ATTN_COMPUTE(1, 576)

    float linv[4];
#pragma unroll
    for (int r = 0; r < 4; ++r) linv[r] = 1.0f / __shfl(l_run, 4 * hi + r);
#pragma unroll
    for (int r = 0; r < 4; ++r) {
        int row = qt0 + 16 * wv + 4 * hi + r;
        if (row >= NQ) continue;
        size_t base = ((size_t)b * NQ + row) * CDIM + h * HDIM;
#pragma unroll
        for (int dj = 0; dj < 4; ++dj)
            ob[base + dj * 16 + lo] = f2bf(accO[dj][r] * linv[r]);
    }
}

extern "C" void kernel_launch(void* const* d_in, const int* in_sizes, int n_in,
                              void* d_out, int out_size, void* d_ws, size_t ws_size,
                              hipStream_t stream) {
    (void)in_sizes; (void)n_in; (void)out_size; (void)ws_size;
    const float* x      = (const float*)d_in[0];
    const float* qkv_w  = (const float*)d_in[1];
    const float* proj_w = (const float*)d_in[2];
    const float* proj_b = (const float*)d_in[3];
    const float* mask   = (const float*)d_in[4];
    float* out = (float*)d_out;

    const size_t x_elems  = (size_t)MROWS * CDIM;                 // 14,180,352
    const size_t w_elems  = (size_t)3 * CDIM * CDIM;              //  1,769,472
    const size_t pw_elems = (size_t)CDIM * CDIM;                  //    589,824
    const size_t mk_elems = (size_t)NH * NQ * MK_STRIDE;          //  4,431,360
    const size_t qk_elems = (size_t)B_SZ * NH * NQ * HDIM;        // 14,180,352
    const size_t vt_elems = (size_t)B_SZ * NH * HDIM * VT_STRIDE; // 15,728,640

    unsigned short* xb    = (unsigned short*)d_ws;   // reused as attn-out later
    unsigned short* wb    = xb + x_elems;
    unsigned short* pwb   = wb + w_elems;
    unsigned short* mkb   = pwb + pw_elems;
    unsigned short* vtbuf = mkb + mk_elems;
    unsigned short* qbuf  = vtbuf + vt_elems;
    unsigned short* kbuf  = qbuf + qk_elems;
    unsigned short* aobuf = xb;
    // total ws use: ~130.1 MB

    cvt_bf16<<<1024, 256, 0, stream>>>(x, xb, (int)(x_elems / 8));
    cvt_bf16<<<256, 256, 0, stream>>>(qkv_w, wb, (int)(w_elems / 8));
    cvt_bf16<<<128, 256, 0, stream>>>(proj_w, pwb, (int)(pw_elems / 8));
    cvt_mask<<<(NH * NQ * (MK_STRIDE / 8) + 255) / 256, 256, 0, stream>>>(mask, mkb);
    qkv_gemm<<<145 * 18, 256, 0, stream>>>(xb, wb, qbuf, kbuf, vtbuf);
    attn_fused<<<12 * 32 * 10, 256, 0, stream>>>(qbuf, kbuf, vtbuf, mkb, aobuf);
    proj_gemm<<<73 * 3, 512, 0, stream>>>(aobuf, pwb, proj_b, out);
}

// Round 18
// 266.950 us; speedup vs baseline: 1.1466x; 1.1466x over previous
//
#include <hip/hip_runtime.h>
#include <stdint.h>
#include <stddef.h>

#define B_SZ 32
#define NQ 577
#define CDIM 768
#define NH 12
#define HDIM 64
#define MROWS (B_SZ * NQ)     // 18464
#define KDIM CDIM             // 768
#define NKT (KDIM / 64)       // 12 K-tiles of 64 (8-phase GEMMs)
#define VT_STRIDE 640
#define MK_STRIDE 640
#define SCALE_F 0.125f

typedef __bf16 bf16x8 __attribute__((ext_vector_type(8)));
typedef float f32x4 __attribute__((ext_vector_type(4)));
typedef unsigned short u16x8 __attribute__((ext_vector_type(8)));
typedef unsigned short u16x4 __attribute__((ext_vector_type(4)));

__device__ __forceinline__ unsigned short f2bf(float f) {
    unsigned int u = __builtin_bit_cast(unsigned int, f);
    return (unsigned short)((u + 0x7fffu + ((u >> 16) & 1u)) >> 16);  // RNE
}
__device__ __forceinline__ float bf2f(unsigned short u) {
    unsigned int v = ((unsigned int)u) << 16;
    return __builtin_bit_cast(float, v);
}

__device__ __forceinline__ f32x4 mfma16(bf16x8 a, bf16x8 b, f32x4 c) {
    return __builtin_amdgcn_mfma_f32_16x16x32_bf16(a, b, c, 0, 0, 0);
}

__device__ __forceinline__ void gll16(const void* g, void* l) {
    __builtin_amdgcn_global_load_lds(
        (const __attribute__((address_space(1))) void*)g,
        (__attribute__((address_space(3))) void*)l, 16, 0, 0);
}

// ---------------- fp32 -> bf16 bulk convert
__global__ __launch_bounds__(256) void cvt_bf16(
    const float* __restrict__ src, unsigned short* __restrict__ dst, int n8)
{
    int i = blockIdx.x * blockDim.x + threadIdx.x;
    int stride = gridDim.x * blockDim.x;
    for (; i < n8; i += stride) {
        const float* p = src + (size_t)i * 8;
        f32x4 v0 = *(const f32x4*)p;
        f32x4 v1 = *(const f32x4*)(p + 4);
        u16x8 u;
        u[0] = f2bf(v0[0]); u[1] = f2bf(v0[1]); u[2] = f2bf(v0[2]); u[3] = f2bf(v0[3]);
        u[4] = f2bf(v1[0]); u[5] = f2bf(v1[1]); u[6] = f2bf(v1[2]); u[7] = f2bf(v1[3]);
        *(u16x8*)(dst + (size_t)i * 8) = u;
    }
}

// ---------------- mask fp32 [6924][577] -> bf16 [6924][640] (zero-padded)
__global__ __launch_bounds__(256) void cvt_mask(
    const float* __restrict__ src, unsigned short* __restrict__ dst)
{
    const int CH = MK_STRIDE / 8;  // 80
    int i = blockIdx.x * blockDim.x + threadIdx.x;
    int total = NH * NQ * CH;
    if (i >= total) return;
    int row = i / CH, c8 = (i % CH) * 8;
    const float* s = src + (size_t)row * NQ;
    u16x8 u;
#pragma unroll
    for (int j = 0; j < 8; ++j) {
        int c = c8 + j;
        u[j] = (c < NQ) ? f2bf(s[c]) : (unsigned short)0;
    }
    *(u16x8*)(dst + (size_t)row * MK_STRIDE + c8) = u;
}

// ---------------- v [B*H][N][64] -> V^T [B*H][64][640] tile transpose
// 64x64 LDS tile (pad 73 to spread banks); rows clamped; pad cols 577..639 get
// clamped-row duplicates (finite; attn masks them via P=0).
__global__ __launch_bounds__(256) void transpose_v(
    const unsigned short* __restrict__ vb, unsigned short* __restrict__ vtb)
{
    __shared__ unsigned short tile[64][73];
    const int tid = threadIdx.x;
    const int bh = blockIdx.x / 10;
    const int n0 = (blockIdx.x % 10) * 64;

    for (int c = tid; c < 512; c += 256) {
        int row = c >> 3, col8 = (c & 7) * 8;
        int n = n0 + row; if (n > NQ - 1) n = NQ - 1;
        u16x8 v = *(const u16x8*)(vb + ((size_t)bh * NQ + n) * HDIM + col8);
        *(u16x8*)&tile[row][col8] = v;
    }
    __syncthreads();
    for (int c = tid; c < 512; c += 256) {
        int d = c >> 3, nc8 = (c & 7) * 8;
        u16x8 w;
#pragma unroll
        for (int j = 0; j < 8; ++j) w[j] = tile[nc8 + j][d];
        *(u16x8*)(vtb + ((size_t)bh * HDIM + d) * VT_STRIDE + n0 + nc8) = w;
    }
}

// ================= 256x256x(BK=64) 8-phase template (r11-verified mainloop) ==
#define STAGE_HT8(SC, A_PTR, B_PTR)                                                \
    { const int _t = (SC) >> 2, _p = (SC) & 3;                                     \
      if (_t < NKT) {                                                              \
        const int _kh = _p >> 1;                                                   \
        unsigned short* _dst = (_p & 1) ? &Bl[_t & 1][_kh][0] : &Al[_t & 1][_kh][0];\
        const unsigned short* _sb = (_p & 1) ? (B_PTR) : (A_PTR);                  \
        const int _rb = ((_p & 1) ? nt : mt) * 256;                                \
        const int _k = _t * 64 + _kh * 32;                                         \
        const int _c0 = tid, _c1 = tid + 512;                                      \
        const int _g0 = _c0 ^ ((_c0 >> 3) & 7), _g1 = _c1 ^ ((_c1 >> 3) & 7);      \
        int _r0 = _rb + (_g0 >> 2), _r1 = _rb + (_g1 >> 2);                        \
        if (!(_p & 1)) {                                                           \
            if (_r0 >= MROWS) _r0 = MROWS - 1;                                     \
            if (_r1 >= MROWS) _r1 = MROWS - 1;                                     \
        }                                                                          \
        gll16(_sb + (size_t)_r0 * KDIM + _k + (_g0 & 3) * 8, _dst + _c0 * 8);      \
        gll16(_sb + (size_t)_r1 * KDIM + _k + (_g1 & 3) * 8, _dst + _c1 * 8);      \
      } else {                                                                     \
        gll16(A_PTR, &Scr[tid * 8]);                                               \
        gll16(A_PTR, &Scr[(tid + 512) * 8]);                                       \
      } }

#define GEMM8_MAINLOOP(A_PTR, B_PTR)                                               \
    const int tid = threadIdx.x;                                                   \
    const int wid = tid >> 6, lane = tid & 63;                                     \
    const int lo = lane & 15, hi = lane >> 4;                                      \
    const int wr = wid >> 2, wcN = wid & 3;                                        \
    f32x4 acc[8][4];                                                               \
    _Pragma("unroll") for (int i = 0; i < 8; ++i)                                  \
        _Pragma("unroll") for (int j = 0; j < 4; ++j)                              \
            acc[i][j] = (f32x4){0.f, 0.f, 0.f, 0.f};                               \
    const int xsw = ((4 * lo + hi) ^ ((lo >> 1) & 7)) * 16;                        \
    _Pragma("unroll") for (int ps = 0; ps < 7; ++ps) { STAGE_HT8(ps, A_PTR, B_PTR) } \
    int sc = 7;                                                                    \
    asm volatile("s_waitcnt vmcnt(6)" ::: "memory");                               \
    __builtin_amdgcn_s_barrier();                                                  \
    for (int t = 0; t < NKT; ++t) {                                                \
        const int db = t & 1;                                                      \
        const char* a0p = (const char*)&Al[db][0][0] + xsw;                        \
        const char* a1p = (const char*)&Al[db][1][0] + xsw;                        \
        const char* b0p = (const char*)&Bl[db][0][0] + xsw;                        \
        const char* b1p = (const char*)&Bl[db][1][0] + xsw;                        \
        bf16x8 a[8], bx[2], by[2];                                                 \
        _Pragma("unroll") for (int mi = 0; mi < 8; ++mi)                           \
            a[mi] = *(const bf16x8*)(a0p + (wr * 8 + mi) * 1024);                  \
        bx[0] = *(const bf16x8*)(b0p + (wcN * 4 + 0) * 1024);                      \
        bx[1] = *(const bf16x8*)(b0p + (wcN * 4 + 1) * 1024);                      \
        asm volatile("" ::: "memory");                                             \
        STAGE_HT8(sc, A_PTR, B_PTR) ++sc;                                          \
        __builtin_amdgcn_s_barrier();                                              \
        __builtin_amdgcn_s_setprio(1);                                             \
        _Pragma("unroll") for (int mi = 0; mi < 8; ++mi) {                         \
            acc[mi][0] = mfma16(a[mi], bx[0], acc[mi][0]);                         \
            acc[mi][1] = mfma16(a[mi], bx[1], acc[mi][1]);                         \
        }                                                                          \
        __builtin_amdgcn_s_setprio(0);                                             \
        __builtin_amdgcn_s_barrier();                                              \
        by[0] = *(const bf16x8*)(b0p + (wcN * 4 + 2) * 1024);                      \
        by[1] = *(const bf16x8*)(b0p + (wcN * 4 + 3) * 1024);                      \
        asm volatile("" ::: "memory");                                             \
        STAGE_HT8(sc, A_PTR, B_PTR) ++sc;                                          \
        __builtin_amdgcn_s_barrier();                                              \
        __builtin_amdgcn_s_setprio(1);                                             \
        _Pragma("unroll") for (int mi = 0; mi < 8; ++mi) {                         \
            acc[mi][2] = mfma16(a[mi], by[0], acc[mi][2]);                         \
            acc[mi][3] = mfma16(a[mi], by[1], acc[mi][3]);                         \
        }                                                                          \
        __builtin_amdgcn_s_setprio(0);                                             \
        __builtin_amdgcn_s_barrier();                                              \
        _Pragma("unroll") for (int mi = 0; mi < 8; ++mi)                           \
            a[mi] = *(const bf16x8*)(a1p + (wr * 8 + mi) * 1024);                  \
        bx[0] = *(const bf16x8*)(b1p + (wcN * 4 + 0) * 1024);                      \
        bx[1] = *(const bf16x8*)(b1p + (wcN * 4 + 1) * 1024);                      \
        asm volatile("" ::: "memory");                                             \
        STAGE_HT8(sc, A_PTR, B_PTR) ++sc;                                          \
        __builtin_amdgcn_s_barrier();                                              \
        __builtin_amdgcn_s_setprio(1);                                             \
        _Pragma("unroll") for (int mi = 0; mi < 8; ++mi) {                         \
            acc[mi][0] = mfma16(a[mi], bx[0], acc[mi][0]);                         \
            acc[mi][1] = mfma16(a[mi], bx[1], acc[mi][1]);                         \
        }                                                                          \
        __builtin_amdgcn_s_setprio(0);                                             \
        __builtin_amdgcn_s_barrier();                                              \
        by[0] = *(const bf16x8*)(b1p + (wcN * 4 + 2) * 1024);                      \
        by[1] = *(const bf16x8*)(b1p + (wcN * 4 + 3) * 1024);                      \
        asm volatile("" ::: "memory");                                             \
        STAGE_HT8(sc, A_PTR, B_PTR) ++sc;                                          \
        asm volatile("s_waitcnt vmcnt(6)" ::: "memory");                           \
        __builtin_amdgcn_s_barrier();                                              \
        __builtin_amdgcn_s_setprio(1);                                             \
        _Pragma("unroll") for (int mi = 0; mi < 8; ++mi) {                         \
            acc[mi][2] = mfma16(a[mi], by[0], acc[mi][2]);                         \
            acc[mi][3] = mfma16(a[mi], by[1], acc[mi][3]);                         \
        }                                                                          \
        __builtin_amdgcn_s_setprio(0);                                             \
        __builtin_amdgcn_s_barrier();                                              \
    }                                                                              \
    asm volatile("s_waitcnt vmcnt(0)" ::: "memory");

// ---------------- Stage 1: QKV GEMM (256^2 8-phase; FULLY COALESCED epilogue —
// v written contiguous [B,H,N,64] to scratch, transposed by transpose_v)
__global__ __launch_bounds__(512, 2) void qkv_gemm(
    const unsigned short* __restrict__ A,
    const unsigned short* __restrict__ Bm,
    unsigned short* __restrict__ qb,
    unsigned short* __restrict__ kb,
    unsigned short* __restrict__ vb)   // contiguous v scratch
{
    __shared__ __align__(16) unsigned short Al[2][2][256 * 32];
    __shared__ __align__(16) unsigned short Bl[2][2][256 * 32];
    __shared__ __align__(16) unsigned short Scr[512 * 16];
    const int NTL = 9;   // 2304/256
    // bijective XCD chunking: nwg = 657 = 8*82+1 -> q=82, r=1
    const int xcd = blockIdx.x & 7, off = blockIdx.x >> 3;
    const int wgid = (xcd < 1 ? xcd * 83 : 83 + (xcd - 1) * 82) + off;
    const int nt = wgid % NTL, mt = wgid / NTL;

    GEMM8_MAINLOOP(A, Bm)

    // this wave's 64 output cols = exactly one (s,h)
    const int cbase = nt * 256 + wcN * 64;
    const int s = cbase / CDIM;
    const int h = (cbase % CDIM) / HDIM;
    unsigned short* dst = (s == 0) ? qb : (s == 1) ? kb : vb;
#pragma unroll
    for (int mi = 0; mi < 8; ++mi) {
#pragma unroll
        for (int r = 0; r < 4; ++r) {
            int m = mt * 256 + wr * 128 + mi * 16 + 4 * hi + r;
            if (m >= MROWS) continue;
            int b = m / NQ, n = m % NQ;
            size_t base = (((size_t)(b * NH + h)) * NQ + n) * HDIM;
#pragma unroll
            for (int nj = 0; nj < 4; ++nj)
                dst[base + nj * 16 + lo] = f2bf(acc[mi][nj][r]);
        }
    }
}

// ---------------- Stage 3: proj GEMM (256^2 8-phase; fp32 out + bias)
__global__ __launch_bounds__(512, 2) void proj_gemm(
    const unsigned short* __restrict__ A,
    const unsigned short* __restrict__ Bm,
    const float* __restrict__ bias,
    float* __restrict__ out)
{
    __shared__ __align__(16) unsigned short Al[2][2][256 * 32];
    __shared__ __align__(16) unsigned short Bl[2][2][256 * 32];
    __shared__ __align__(16) unsigned short Scr[512 * 16];
    const int NTL = 3;   // 768/256
    // nwg = 219 = 8*27+3 -> q=27, r=3
    const int xcd = blockIdx.x & 7, off = blockIdx.x >> 3;
    const int wgid = (xcd < 3 ? xcd * 28 : 84 + (xcd - 3) * 27) + off;
    const int nt = wgid % NTL, mt = wgid / NTL;

    GEMM8_MAINLOOP(A, Bm)

    const int cb = nt * 256 + wcN * 64;
    float bv[4];
#pragma unroll
    for (int nj = 0; nj < 4; ++nj) bv[nj] = bias[cb + nj * 16 + lo];
#pragma unroll
    for (int mi = 0; mi < 8; ++mi) {
#pragma unroll
        for (int r = 0; r < 4; ++r) {
            int m = mt * 256 + wr * 128 + mi * 16 + 4 * hi + r;
            if (m >= MROWS) continue;
#pragma unroll
            for (int nj = 0; nj < 4; ++nj)
                out[(size_t)m * CDIM + cb + nj * 16 + lo] = acc[mi][nj][r] + bv[nj];
        }
    }
}

// ---------------- Stage 2: flash attention (round-11 exact; proven rounds 7-17)
#define STAGE(SEL, KV)                                                        \
    {                                                                         \
        int kr0 = (KV) + srow;      if (kr0 > NQ - 1) kr0 = NQ - 1;           \
        int kr1 = (KV) + srow + 32; if (kr1 > NQ - 1) kr1 = NQ - 1;           \
        gll16(kp + (size_t)kr0 * HDIM + scol, &Ks[SEL][0] + tid * 8);         \
        gll16(kp + (size_t)kr1 * HDIM + scol, &Ks[SEL][2048] + tid * 8);      \
        gll16(vp + (size_t)srow * VT_STRIDE + (KV) + scol, &Vs[SEL][0] + tid * 8); \
        gll16(vp + (size_t)(srow + 32) * VT_STRIDE + (KV) + scol, &Vs[SEL][2048] + tid * 8); \
    }

#define LOADM(MW, KV)                                                         \
    _Pragma("unroll") for (int nj = 0; nj < 4; ++nj)                          \
        MW[nj] = *(const u16x4*)(mrow + (KV) + 16 * nj + 4 * hi);

#define ATTN_COMPUTE(CB, KV)                                                  \
    {                                                                         \
        const int kv0 = (KV);                                                 \
        bf16x8 af0[4], af1[4], bv0[4], bv1[4];                                \
        _Pragma("unroll") for (int nj = 0; nj < 4; ++nj) {                    \
            int kr = 16 * nj + lo;                                            \
            int sw = (kr & 7) << 4;                                           \
            const unsigned short* rowp = &Ks[CB][kr * 64];                    \
            af0[nj] = *(const bf16x8*)(rowp + ((( 0 + 16 * hi) ^ sw) >> 1));  \
            af1[nj] = *(const bf16x8*)(rowp + (((64 + 16 * hi) ^ sw) >> 1));  \
        }                                                                     \
        _Pragma("unroll") for (int dj = 0; dj < 4; ++dj) {                    \
            int dr = 16 * dj + lo;                                            \
            int sw = (dr & 7) << 4;                                           \
            const unsigned short* rowp = &Vs[CB][dr * 64];                    \
            bv0[dj] = *(const bf16x8*)(rowp + ((( 0 + 16 * hi) ^ sw) >> 1));  \
            bv1[dj] = *(const bf16x8*)(rowp + (((64 + 16 * hi) ^ sw) >> 1));  \
        }                                                                     \
        __builtin_amdgcn_s_setprio(1);                                        \
        f32x4 S[4];                                                           \
        _Pragma("unroll") for (int nj = 0; nj < 4; ++nj) {                    \
            f32x4 sv = (f32x4){0.f, 0.f, 0.f, 0.f};                           \
            sv = mfma16(af0[nj], bq0, sv);                                    \
            sv = mfma16(af1[nj], bq1, sv);                                    \
            S[nj] = sv;                                                       \
        }                                                                     \
        __builtin_amdgcn_s_setprio(0);                                        \
        float p[16];                                                          \
        _Pragma("unroll") for (int nj = 0; nj < 4; ++nj)                      \
            _Pragma("unroll") for (int r = 0; r < 4; ++r)                     \
                p[nj * 4 + r] = S[nj][r] * SCALE_F + bf2f(mw[nj][r]);         \
        if (kv0 + 64 > NQ) {                                                  \
            const int rem = NQ - kv0;                                         \
            _Pragma("unroll") for (int nj = 0; nj < 4; ++nj)                  \
                _Pragma("unroll") for (int r = 0; r < 4; ++r)                 \
                    if (16 * nj + 4 * hi + r >= rem) p[nj * 4 + r] = -1e30f;  \
        }                                                                     \
        float m01 = fmaxf(p[0], p[1]),  m23 = fmaxf(p[2], p[3]);              \
        float m45 = fmaxf(p[4], p[5]),  m67 = fmaxf(p[6], p[7]);              \
        float m89 = fmaxf(p[8], p[9]),  mab = fmaxf(p[10], p[11]);            \
        float mcd = fmaxf(p[12], p[13]), mef = fmaxf(p[14], p[15]);           \
        float pmax = fmaxf(fmaxf(fmaxf(m01, m23), fmaxf(m45, m67)),           \
                           fmaxf(fmaxf(m89, mab), fmaxf(mcd, mef)));          \
        pmax = fmaxf(pmax, __shfl_xor(pmax, 16));                             \
        pmax = fmaxf(pmax, __shfl_xor(pmax, 32));                             \
        bool grow = pmax > m_run + 8.f;                                       \
        float mnew = grow ? pmax : m_run;                                     \
        float corr = __expf(m_run - mnew);                                    \
        m_run = mnew;                                                         \
        if (__any((int)grow)) {                                               \
            float c0 = __shfl(corr, 4 * hi + 0);                              \
            float c1 = __shfl(corr, 4 * hi + 1);                              \
            float c2 = __shfl(corr, 4 * hi + 2);                              \
            float c3 = __shfl(corr, 4 * hi + 3);                              \
            _Pragma("unroll") for (int dj = 0; dj < 4; ++dj) {                \
                accO[dj][0] *= c0; accO[dj][1] *= c1;                         \
                accO[dj][2] *= c2; accO[dj][3] *= c3;                         \
            }                                                                 \
        }                                                                     \
        _Pragma("unroll") for (int i = 0; i < 16; ++i)                        \
            p[i] = __expf(p[i] - mnew);                                       \
        float ps = (((p[0]+p[1])+(p[2]+p[3])) + ((p[4]+p[5])+(p[6]+p[7])))    \
                 + (((p[8]+p[9])+(p[10]+p[11])) + ((p[12]+p[13])+(p[14]+p[15])));\
        _Pragma("unroll") for (int nj = 0; nj < 4; ++nj) {                    \
            u16x4 w;                                                          \
            w[0] = f2bf(p[nj*4+0]); w[1] = f2bf(p[nj*4+1]);                   \
            w[2] = f2bf(p[nj*4+2]); w[3] = f2bf(p[nj*4+3]);                   \
            *(u16x4*)&P_lds[wv][lo][16 * nj + 4 * hi] = w;                    \
        }                                                                     \
        ps += __shfl_xor(ps, 16);                                             \
        ps += __shfl_xor(ps, 32);                                             \
        l_run = l_run * corr + ps;                                            \
        const bf16x8 pa0 = *(const bf16x8*)&P_lds[wv][lo][8 * hi];            \
        const bf16x8 pa1 = *(const bf16x8*)&P_lds[wv][lo][32 + 8 * hi];       \
        __builtin_amdgcn_s_setprio(1);                                        \
        _Pragma("unroll") for (int dj = 0; dj < 4; ++dj) {                    \
            accO[dj] = mfma16(pa0, bv0[dj], accO[dj]);                        \
            accO[dj] = mfma16(pa1, bv1[dj], accO[dj]);                        \
        }                                                                     \
        __builtin_amdgcn_s_setprio(0);                                        \
    }

__global__ __launch_bounds__(256) void attn_fused(
    const unsigned short* __restrict__ qb,
    const unsigned short* __restrict__ kb,
    const unsigned short* __restrict__ vtb,
    const unsigned short* __restrict__ maskb,  // [12][577][640] bf16
    unsigned short* __restrict__ ob)           // [B][577][768] bf16
{
    __shared__ unsigned short Ks[2][64 * 64];   // 16 KB
    __shared__ unsigned short Vs[2][64 * 64];   // 16 KB
    __shared__ unsigned short P_lds[4][16][68]; // 8.7 KB
    const int tid = threadIdx.x;
    const int wv = tid >> 6;
    const int lane = tid & 63;
    const int lo = lane & 15, hi = lane >> 4;

    const int xcd = blockIdx.x & 7;
    const int idx = blockIdx.x >> 3;
    const int bh = xcd + 8 * (idx / 10);
    const int qblk = idx % 10;
    const int b = bh / NH, h = bh % NH;
    const int qt0 = qblk * 64;

    const unsigned short* qp = qb + (size_t)bh * NQ * HDIM;
    const unsigned short* kp = kb + (size_t)bh * NQ * HDIM;
    const unsigned short* vp = vtb + (size_t)bh * HDIM * VT_STRIDE;

    const int srow = tid >> 3;                                  // 0..31
    const int scol = ((((tid & 7) << 4) ^ ((srow & 7) << 4)) >> 1); // swizzled src elem

    int qr = qt0 + 16 * wv + lo; if (qr > NQ - 1) qr = NQ - 1;
    const unsigned short* mrow = maskb + ((size_t)h * NQ + qr) * MK_STRIDE;
    const bf16x8 bq0 = *(const bf16x8*)(qp + (size_t)qr * HDIM + 8 * hi);
    const bf16x8 bq1 = *(const bf16x8*)(qp + (size_t)qr * HDIM + 32 + 8 * hi);

    float m_run = -1e30f, l_run = 0.f;
    f32x4 accO[4];
#pragma unroll
    for (int dj = 0; dj < 4; ++dj) accO[dj] = (f32x4){0.f, 0.f, 0.f, 0.f};

    u16x4 mw[4];
    STAGE(0, 0)
    for (int t = 0; t < 9; ++t) {
        const int kv0 = t * 64;
        LOADM(mw, kv0)
        asm volatile("" ::: "memory");
        STAGE((t + 1) & 1, kv0 + 64)
        asm volatile("s_waitcnt vmcnt(8)" ::: "memory");
        __builtin_amdgcn_s_barrier();
        asm volatile("" ::: "memory");
        ATTN_COMPUTE(t & 1, kv0)
        asm volatile("" ::: "memory");
        __builtin_amdgcn_s_barrier();
    }
    LOADM(mw, 576)
    asm volatile("s_waitcnt vmcnt(4)" ::: "memory");
    __builtin_amdgcn_s_barrier();
    asm volatile("" ::: "memory");
    ATTN_COMPUTE(1, 576)

    float linv[4];
#pragma unroll
    for (int r = 0; r < 4; ++r) linv[r] = 1.0f / __shfl(l_run, 4 * hi + r);
#pragma unroll
    for (int r = 0; r < 4; ++r) {
        int row = qt0 + 16 * wv + 4 * hi + r;
        if (row >= NQ) continue;
        size_t base = ((size_t)b * NQ + row) * CDIM + h * HDIM;
#pragma unroll
        for (int dj = 0; dj < 4; ++dj)
            ob[base + dj * 16 + lo] = f2bf(accO[dj][r] * linv[r]);
    }
}

extern "C" void kernel_launch(void* const* d_in, const int* in_sizes, int n_in,
                              void* d_out, int out_size, void* d_ws, size_t ws_size,
                              hipStream_t stream) {
    (void)in_sizes; (void)n_in; (void)out_size; (void)ws_size;
    const float* x      = (const float*)d_in[0];
    const float* qkv_w  = (const float*)d_in[1];
    const float* proj_w = (const float*)d_in[2];
    const float* proj_b = (const float*)d_in[3];
    const float* mask   = (const float*)d_in[4];
    float* out = (float*)d_out;

    const size_t x_elems  = (size_t)MROWS * CDIM;                 // 14,180,352
    const size_t w_elems  = (size_t)3 * CDIM * CDIM;              //  1,769,472
    const size_t pw_elems = (size_t)CDIM * CDIM;                  //    589,824
    const size_t mk_elems = (size_t)NH * NQ * MK_STRIDE;          //  4,431,360
    const size_t qk_elems = (size_t)B_SZ * NH * NQ * HDIM;        // 14,180,352
    const size_t vt_elems = (size_t)B_SZ * NH * HDIM * VT_STRIDE; // 15,728,640

    unsigned short* xb    = (unsigned short*)d_ws;   // reused as attn-out later
    unsigned short* wb    = xb + x_elems;
    unsigned short* pwb   = wb + w_elems;
    unsigned short* mkb   = pwb + pw_elems;
    unsigned short* vtbuf = mkb + mk_elems;
    unsigned short* qbuf  = vtbuf + vt_elems;
    unsigned short* kbuf  = qbuf + qk_elems;
    unsigned short* aobuf = xb;
    // contiguous-v scratch lives in d_out (28.4 MB <= 56.7 MB), dead before proj writes
    unsigned short* vbuf  = (unsigned short*)d_out;

    cvt_bf16<<<1024, 256, 0, stream>>>(x, xb, (int)(x_elems / 8));
    cvt_bf16<<<256, 256, 0, stream>>>(qkv_w, wb, (int)(w_elems / 8));
    cvt_bf16<<<128, 256, 0, stream>>>(proj_w, pwb, (int)(pw_elems / 8));
    cvt_mask<<<(NH * NQ * (MK_STRIDE / 8) + 255) / 256, 256, 0, stream>>>(mask, mkb);
    qkv_gemm<<<73 * 9, 512, 0, stream>>>(xb, wb, qbuf, kbuf, vbuf);
    transpose_v<<<B_SZ * NH * 10, 256, 0, stream>>>(vbuf, vtbuf);
    attn_fused<<<12 * 32 * 10, 256, 0, stream>>>(qbuf, kbuf, vtbuf, mkb, aobuf);
    proj_gemm<<<73 * 3, 512, 0, stream>>>(aobuf, pwb, proj_b, out);
}